// Round 4
// baseline (220.870 us; speedup 1.0000x reference)
//
#include <hip/hip_runtime.h>
#include <math.h>

#define Bn 4
#define Cn 64
#define On 64
#define Hn 128
#define Wn 128
#define Kn 9
#define HWn (Hn*Wn)
#define ZROW 16384            // per-batch zero row index in xT
#define XBSTRIDE (16385*64)   // per-batch stride of xT (16384 rows + 1 zero row)

typedef short v8s __attribute__((ext_vector_type(8)));
typedef float v4f __attribute__((ext_vector_type(4)));

__device__ inline unsigned short f2bf(float f) {
  unsigned u = __builtin_bit_cast(unsigned, f);
  u += 0x7fff + ((u >> 16) & 1);          // RNE
  return (unsigned short)(u >> 16);
}
__device__ inline float bf2f(unsigned short h) {
  unsigned u = ((unsigned)h) << 16;
  return __builtin_bit_cast(float, u);
}
__device__ inline unsigned short f2h(float f) {
  _Float16 h = (_Float16)f;
  return __builtin_bit_cast(unsigned short, h);
}
__device__ inline float h2f(unsigned v) {
  _Float16 h = __builtin_bit_cast(_Float16, (unsigned short)(v & 0xffff));
  return (float)h;
}

// ---------------------------------------------------------------------------
// K1: blocks 0..511: x_main NCHW fp32 -> xT NHWC bf16; block 512: Wfrag
//     repack (16x16x32 A-frag order) + per-batch zero rows.
// ---------------------------------------------------------------------------
__global__ __launch_bounds__(256) void k_misc(
    const float* __restrict__ x_main,
    const float* __restrict__ weight,
    unsigned short* __restrict__ xT,
    unsigned short* __restrict__ Wfrag)
{
  const int blk = blockIdx.x;
  const int t = threadIdx.x;
  const int lane = t & 63;

  if (blk < 512) {
    __shared__ float tile[64 * 129];
    int b  = blk >> 7;
    int p0 = (blk & 127) << 7;
    int grp = t >> 6;
    const float* src = x_main + b * Cn * HWn + p0;
    #pragma unroll
    for (int i = 0; i < 16; ++i) {
      int c = i * 4 + grp;
      tile[c * 129 + lane]      = src[c * HWn + lane];
      tile[c * 129 + 64 + lane] = src[c * HWn + 64 + lane];
    }
    __syncthreads();
    unsigned short* dst = xT + b * XBSTRIDE + p0 * 64;
    #pragma unroll
    for (int i = 0; i < 32; ++i) {
      int p = i * 4 + grp;
      dst[p * 64 + lane] = f2bf(tile[lane * 129 + p]);   // stride 129: no conflict
    }
  } else {
    // Wfrag: A[m=ot*16+(ln&15)][c=hk*32+(ln>>4)*8+j] for (k, ot, hk)
    for (int idx = t; idx < 36864; idx += 256) {
      int j  = idx & 7;
      int ln = (idx >> 3) & 63;
      int hk = (idx >> 9) & 1;
      int ot = (idx >> 10) & 3;
      int k  = idx >> 12;
      int o = ot * 16 + (ln & 15);
      int c = hk * 32 + (ln >> 4) * 8 + j;
      Wfrag[idx] = f2bf(weight[(o * Cn + c) * Kn + k]);
    }
    if (t < 256) {
      int b = t >> 6, c = t & 63;
      xT[b * XBSTRIDE + ZROW * 64 + c] = 0;
    }
  }
}

// ---------------------------------------------------------------------------
// K2: offset conv -> gather records. Block = (b, h, 64 w's), 4 waves c-split.
//     Own kernel => LDS 29.7KB => 5 blocks/CU (vs 2 when merged).
// ---------------------------------------------------------------------------
__global__ __launch_bounds__(256) void k_conv(
    const float* __restrict__ x_extra,
    const float* __restrict__ pre_offset,
    const float* __restrict__ pre_sim,
    const float* __restrict__ w_om,
    const float* __restrict__ b_om,
    uint4* __restrict__ OFS)
{
  __shared__ float s_buf[4 * 64 * 29];
  const int t = threadIdx.x;
  const int lane = t & 63;
  const int wv = __builtin_amdgcn_readfirstlane(t >> 6);
  const int blk = blockIdx.x;
  const int b  = blk >> 8;
  const int hs = blk & 255;
  const int h  = hs >> 1;
  const int w0 = (hs & 1) << 6;
  const int w  = w0 + lane;

  float acc[27];
  #pragma unroll
  for (int j = 0; j < 27; ++j) acc[j] = 0.f;
  {
    const float* xe = x_extra + (b * Cn + wv * 16) * HWn;
    #pragma unroll 2
    for (int ci = 0; ci < 16; ++ci) {
      const float* xc = xe + ci * HWn;
      float tap[9];
      #pragma unroll
      for (int r = 0; r < 3; ++r) {
        int hh = h - 1 + r;
        bool hv = (hh >= 0) & (hh < Hn);
        #pragma unroll
        for (int s = 0; s < 3; ++s) {
          int ww = w - 1 + s;
          bool vv = hv & (ww >= 0) & (ww < Wn);
          tap[r * 3 + s] = vv ? xc[hh * Wn + ww] : 0.f;
        }
      }
      const float* wp = w_om + (wv * 16 + ci) * 9;   // w_om[j][c][q], wave-uniform
      #pragma unroll
      for (int j = 0; j < 27; ++j) {
        #pragma unroll
        for (int q = 0; q < 9; ++q)
          acc[j] = fmaf(tap[q], wp[j * 576 + q], acc[j]);
      }
    }
  }
  #pragma unroll
  for (int j = 0; j < 27; ++j)
    s_buf[(wv * 64 + lane) * 29 + j] = acc[j];       // stride 29: conflict-free
  __syncthreads();

  if (wv < 3) {
    #pragma unroll
    for (int kk = 0; kk < 3; ++kk) {
      int k = wv * 3 + kk;
      float sy = b_om[2 * k], sx = b_om[2 * k + 1], sm = b_om[18 + k];
      #pragma unroll
      for (int q = 0; q < 4; ++q) {
        const float* rp = &s_buf[(q * 64 + lane) * 29];
        sy += rp[2 * k];
        sx += rp[2 * k + 1];
        sm += rp[18 + k];
      }
      int pbase = ((b * Kn + k) * Hn + h) * Wn + w;
      float py = 10.f * tanhf(sy) + pre_offset[pbase * 2 + 1] + (float)(h - 1 + k / 3);
      float px = 10.f * tanhf(sx) + pre_offset[pbase * 2 + 0] + (float)(w - 1 + k % 3);
      float m  = 1.f / (1.f + expf(-sm * pre_sim[pbase]));
      float fy = floorf(py), fx = floorf(px);
      float dy = py - fy, dx = px - fx;
      int y0 = (int)fy, x0 = (int)fx;
      int y1 = y0 + 1, x1 = x0 + 1;
      bool vy0 = (y0 >= 0) & (y0 < Hn), vy1 = (y1 >= 0) & (y1 < Hn);
      bool vx0 = (x0 >= 0) & (x0 < Wn), vx1 = (x1 >= 0) & (x1 < Wn);
      unsigned r00 = (vy0 & vx0) ? (unsigned)(y0 * Wn + x0) : ZROW;
      unsigned r01 = (vy0 & vx1) ? (unsigned)(y0 * Wn + x1) : ZROW;
      unsigned r10 = (vy1 & vx0) ? (unsigned)(y1 * Wn + x0) : ZROW;
      unsigned r11 = (vy1 & vx1) ? (unsigned)(y1 * Wn + x1) : ZROW;
      float wy0 = 1.f - dy, wx0 = 1.f - dx;
      uint4 rec;
      rec.x = r00 | (r01 << 16);
      rec.y = r10 | (r11 << 16);
      rec.z = (unsigned)f2h(wy0 * wx0 * m) | ((unsigned)f2h(wy0 * dx * m) << 16);
      rec.w = (unsigned)f2h(dy * wx0 * m) | ((unsigned)f2h(dy * dx * m) << 16);
      OFS[((((b * Hn + h) * 8) + (w >> 4)) * Kn + k) * 16 + (w & 15)] = rec;
    }
  }
}

// ---------------------------------------------------------------------------
// K3 main: LDS-free, barrier-free. One wave = (b, h, 16-pixel group).
// Lane (kq=lane>>4, n=lane&15) builds its B-fragment chunk (8 channels of
// pixel n) directly in registers from 4 bf16 NHWC corner loads, fp32 interp,
// RNE pack. 8x mfma_f32_16x16x32_bf16 per k. No __syncthreads anywhere.
// ---------------------------------------------------------------------------
__global__ __launch_bounds__(256, 4) void dcn_main(
    const unsigned short* __restrict__ xT,
    const unsigned short* __restrict__ Wfrag,
    const uint4* __restrict__ OFS,
    const float* __restrict__ bias,
    float* __restrict__ out)
{
  const int t    = threadIdx.x;
  const int lane = t & 63;
  const int wv   = t >> 6;
  const int blk  = blockIdx.x;
  const int b    = blk >> 8;
  const int h    = (blk >> 1) & 127;
  const int wq   = (blk & 1) * 4 + wv;        // 16-pixel group (0..7)

  const int kq = lane >> 4;                   // c-subgroup (0..3)
  const int n  = lane & 15;                   // pixel within tile

  const unsigned short* xb = xT + b * XBSTRIDE;
  const uint4* recs = OFS + (((b * Hn + h) * 8) + wq) * (Kn * 16);

  v4f acc0 = {0,0,0,0}, acc1 = {0,0,0,0}, acc2 = {0,0,0,0}, acc3 = {0,0,0,0};
  const v8s* Wf = (const v8s*)Wfrag;

  for (int k = 0; k < Kn; ++k) {
    uint4 rec = recs[k * 16 + n];             // dwordx4, 4x dup across kq: 256B/wave
    float w00 = h2f(rec.z), w01 = h2f(rec.z >> 16);
    float w10 = h2f(rec.w), w11 = h2f(rec.w >> 16);
    unsigned o00 = (rec.x & 0xffff) * 64 + kq * 8;
    unsigned o01 = (rec.x >> 16)    * 64 + kq * 8;
    unsigned o10 = (rec.y & 0xffff) * 64 + kq * 8;
    unsigned o11 = (rec.y >> 16)    * 64 + kq * 8;

    const v8s* wk = Wf + (k * 8) * 64 + lane; // A-frags: Wf[((k*4+ot)*2+hk)*64+lane]

    #pragma unroll
    for (int half = 0; half < 2; ++half) {
      v8s c00 = *(const v8s*)(xb + o00 + half * 32);
      v8s c01 = *(const v8s*)(xb + o01 + half * 32);
      v8s c10 = *(const v8s*)(xb + o10 + half * 32);
      v8s c11 = *(const v8s*)(xb + o11 + half * 32);
      v8s Bf;
      #pragma unroll
      for (int j = 0; j < 8; ++j) {
        float s = fmaf(bf2f((unsigned short)c00[j]), w00,
                  fmaf(bf2f((unsigned short)c01[j]), w01,
                  fmaf(bf2f((unsigned short)c10[j]), w10,
                       bf2f((unsigned short)c11[j]) * w11)));
        Bf[j] = (short)f2bf(s);
      }
      v8s A0 = wk[(0 * 2 + half) * 64];
      v8s A1 = wk[(1 * 2 + half) * 64];
      v8s A2 = wk[(2 * 2 + half) * 64];
      v8s A3 = wk[(3 * 2 + half) * 64];
      acc0 = __builtin_amdgcn_mfma_f32_16x16x32_bf16(A0, Bf, acc0, 0, 0, 0);
      acc1 = __builtin_amdgcn_mfma_f32_16x16x32_bf16(A1, Bf, acc1, 0, 0, 0);
      acc2 = __builtin_amdgcn_mfma_f32_16x16x32_bf16(A2, Bf, acc2, 0, 0, 0);
      acc3 = __builtin_amdgcn_mfma_f32_16x16x32_bf16(A3, Bf, acc3, 0, 0, 0);
    }
  }

  // epilogue: D col=lane&15 (pix), row=kq*4+reg (o within 16-o tile)
  const float4* b4 = (const float4*)bias;
  float4 vb0 = b4[0 * 4 + kq], vb1 = b4[1 * 4 + kq];
  float4 vb2 = b4[2 * 4 + kq], vb3 = b4[3 * 4 + kq];
  float* ob = out + (b * On) * HWn + h * Wn + wq * 16 + n;
  #pragma unroll
  for (int reg = 0; reg < 4; ++reg) {
    ob[(0 * 16 + kq * 4 + reg) * HWn] = acc0[reg] + ((const float*)&vb0)[reg];
    ob[(1 * 16 + kq * 4 + reg) * HWn] = acc1[reg] + ((const float*)&vb1)[reg];
    ob[(2 * 16 + kq * 4 + reg) * HWn] = acc2[reg] + ((const float*)&vb2)[reg];
    ob[(3 * 16 + kq * 4 + reg) * HWn] = acc3[reg] + ((const float*)&vb3)[reg];
  }
}

extern "C" void kernel_launch(void* const* d_in, const int* in_sizes, int n_in,
                              void* d_out, int out_size, void* d_ws, size_t ws_size,
                              hipStream_t stream) {
  const float* x_main     = (const float*)d_in[0];
  const float* x_extra    = (const float*)d_in[1];
  const float* pre_offset = (const float*)d_in[2];
  const float* pre_sim    = (const float*)d_in[3];
  const float* weight     = (const float*)d_in[4];
  const float* bias       = (const float*)d_in[5];
  const float* w_om       = (const float*)d_in[6];
  const float* b_om       = (const float*)d_in[7];
  float* out = (float*)d_out;

  char* ws = (char*)d_ws;
  unsigned short* xT    = (unsigned short*)(ws);              //  8,389,120 B
  unsigned short* Wfrag = (unsigned short*)(ws + 8389120);    //     73,728 B
  uint4*          OFS   = (uint4*)(ws + 8462848);             //  9,437,184 B

  k_misc<<<513, 256, 0, stream>>>(x_main, weight, xT, Wfrag);
  k_conv<<<1024, 256, 0, stream>>>(x_extra, pre_offset, pre_sim, w_om, b_om, OFS);
  dcn_main<<<1024, 256, 0, stream>>>(xT, Wfrag, OFS, bias, out);
}

// Round 5
// 179.243 us; speedup vs baseline: 1.2322x; 1.2322x over previous
//
#include <hip/hip_runtime.h>
#include <math.h>

#define Bn 4
#define Cn 64
#define On 64
#define Hn 128
#define Wn 128
#define Kn 9
#define HWn (Hn*Wn)
#define ZROW 16384            // per-batch zero row index
#define XBSTRIDE (16385*64)   // per-batch stride (16384 rows + 1 zero row)

typedef short v8s __attribute__((ext_vector_type(8)));
typedef _Float16 v8h __attribute__((ext_vector_type(8)));
typedef float v4f __attribute__((ext_vector_type(4)));

__device__ inline unsigned short f2bf(float f) {
  unsigned u = __builtin_bit_cast(unsigned, f);
  u += 0x7fff + ((u >> 16) & 1);          // RNE
  return (unsigned short)(u >> 16);
}
__device__ inline float bf2f(unsigned short h) {
  unsigned u = ((unsigned)h) << 16;
  return __builtin_bit_cast(float, u);
}
__device__ inline unsigned short f2h(float f) {
  _Float16 h = (_Float16)f;
  return __builtin_bit_cast(unsigned short, h);
}
__device__ inline float h2f(unsigned v) {
  _Float16 h = __builtin_bit_cast(_Float16, (unsigned short)(v & 0xffff));
  return (float)h;
}

// ---------------------------------------------------------------------------
// K1 prep:
//   blk 0..1023   : x_main  NCHW fp32 -> xT  NHWC bf16 (64-px tiles)
//   blk 1024..2047: x_extra NCHW fp32 -> xeF NHWC f16
//   blk 2048      : Wfrag repack (main GEMM A-frags, bf16),
//                   WOMfrag repack (conv A-frags, f16, j padded to 32),
//                   zero rows for xT and xeF.
// ---------------------------------------------------------------------------
__global__ __launch_bounds__(256) void k_prep(
    const float* __restrict__ x_main,
    const float* __restrict__ x_extra,
    const float* __restrict__ weight,
    const float* __restrict__ w_om,
    unsigned short* __restrict__ xT,
    _Float16* __restrict__ xeF,
    unsigned short* __restrict__ Wfrag,
    _Float16* __restrict__ WOMfrag)
{
  const int blk = blockIdx.x;
  const int t = threadIdx.x;
  const int lane = t & 63;
  const int grp = t >> 6;

  if (blk < 2048) {
    __shared__ float tile[64 * 65];
    int isExtra = blk >> 10;
    int b  = (blk >> 8) & 3;
    int p0 = (blk & 255) << 6;
    const float* src = (isExtra ? x_extra : x_main) + b * Cn * HWn + p0;
    #pragma unroll
    for (int i = 0; i < 16; ++i) {
      int c = i * 4 + grp;
      tile[c * 65 + lane] = src[c * HWn + lane];     // 256B coalesced
    }
    __syncthreads();
    if (!isExtra) {
      unsigned short* dst = xT + b * XBSTRIDE + p0 * 64;
      #pragma unroll
      for (int i = 0; i < 16; ++i) {
        int p = i * 4 + grp;
        dst[p * 64 + lane] = f2bf(tile[lane * 65 + p]);   // stride65: no conflict
      }
    } else {
      _Float16* dst = xeF + b * XBSTRIDE + p0 * 64;
      #pragma unroll
      for (int i = 0; i < 16; ++i) {
        int p = i * 4 + grp;
        dst[p * 64 + lane] = (_Float16)tile[lane * 65 + p];
      }
    }
  } else {
    // main-GEMM weights: A[o=ot*16+(ln&15)][c=hk*32+(ln>>4)*8+j] for (k,ot,hk)
    for (int idx = t; idx < 36864; idx += 256) {
      int j  = idx & 7;
      int ln = (idx >> 3) & 63;
      int hk = (idx >> 9) & 1;
      int ot = (idx >> 10) & 3;
      int k  = idx >> 12;
      int o = ot * 16 + (ln & 15);
      int c = hk * 32 + (ln >> 4) * 8 + j;
      Wfrag[idx] = f2bf(weight[(o * Cn + c) * Kn + k]);
    }
    // conv weights: order (k9, half, jt, lane, j); j-rows 27..31 zero
    for (int idx = t; idx < 18432; idx += 256) {
      int j    = idx & 7;
      int ln   = (idx >> 3) & 63;
      int jt   = (idx >> 9) & 1;
      int half = (idx >> 10) & 1;
      int k9   = idx >> 11;
      int jo = jt * 16 + (ln & 15);
      int c  = half * 32 + (ln >> 4) * 8 + j;
      float v = (jo < 27) ? w_om[(jo * Cn + c) * Kn + k9] : 0.f;
      WOMfrag[idx] = (_Float16)v;
    }
    if (t < 256) {
      int b = t >> 6, c = t & 63;
      xT[b * XBSTRIDE + ZROW * 64 + c] = 0;
      xeF[b * XBSTRIDE + ZROW * 64 + c] = (_Float16)0.f;
    }
  }
}

// ---------------------------------------------------------------------------
// K2 fused, barrier-free. Block = (b, h, 64 w's), wave = 16 pixels.
// Phase 1: conv via mfma_f32_16x16x32_f16 (register-direct taps from xeF,
//          zero-row for borders) -> 27 j-values/pixel in per-wave LDS.
// Phase 2: per-wave record build (tanh/sigmoid/floor -> {rows, f16 weights})
//          into per-wave LDS.
// Phase 3: main GEMM (round-4 structure), records read from LDS.
// ---------------------------------------------------------------------------
__global__ __launch_bounds__(256, 4) void k_fused(
    const unsigned short* __restrict__ xT,
    const _Float16* __restrict__ xeF,
    const unsigned short* __restrict__ Wfrag,
    const _Float16* __restrict__ WOMfrag,
    const float* __restrict__ pre_offset,
    const float* __restrict__ pre_sim,
    const float* __restrict__ b_om,
    const float* __restrict__ bias,
    float* __restrict__ out)
{
  __shared__ float jbuf[4 * 16 * 36];    // per-wave j-values, stride 36
  __shared__ uint4 recbuf[4 * 16 * 9];   // per-wave gather records

  const int t    = threadIdx.x;
  const int lane = t & 63;
  const int wv   = __builtin_amdgcn_readfirstlane(t >> 6);
  const int blk  = blockIdx.x;
  const int b    = blk >> 8;
  const int h    = (blk >> 1) & 127;
  const int wq   = (blk & 1) * 4 + wv;   // 16-pixel group (0..7)
  const int kq   = lane >> 4;            // c-subgroup / j-subgroup
  const int n    = lane & 15;            // pixel within tile
  const int w    = wq * 16 + n;

  // ---- Phase 1: offset conv on MFMA
  unsigned tapoff[9];
  #pragma unroll
  for (int k9 = 0; k9 < 9; ++k9) {
    int r  = h - 1 + k9 / 3;
    int cc = w - 1 + k9 % 3;
    bool v = ((unsigned)r < (unsigned)Hn) & ((unsigned)cc < (unsigned)Wn);
    tapoff[k9] = (v ? (unsigned)(r * Wn + cc) : (unsigned)ZROW) * 64u;
  }

  const _Float16* xe = xeF + b * XBSTRIDE;
  const v8h* Wom = (const v8h*)WOMfrag;
  v4f ca0 = {0,0,0,0}, ca1 = {0,0,0,0};
  for (int k9 = 0; k9 < 9; ++k9) {
    #pragma unroll
    for (int half = 0; half < 2; ++half) {
      int abase = ((k9 * 2 + half) * 2) * 64 + lane;
      v8h A0 = Wom[abase];
      v8h A1 = Wom[abase + 64];
      v8h Bt = *(const v8h*)(xe + tapoff[k9] + half * 32 + kq * 8);
      ca0 = __builtin_amdgcn_mfma_f32_16x16x32_f16(A0, Bt, ca0, 0, 0, 0);
      ca1 = __builtin_amdgcn_mfma_f32_16x16x32_f16(A1, Bt, ca1, 0, 0, 0);
    }
  }

  // D: col=lane&15 (pixel), row=kq*4+reg (j). Stride-36 rows: 2-way = free.
  float* jb = jbuf + wv * (16 * 36);
  *(v4f*)(jb + n * 36 + kq * 4)      = ca0;   // j 0..15
  *(v4f*)(jb + n * 36 + 16 + kq * 4) = ca1;   // j 16..31

  // ---- Phase 2: records (same wave reads its own LDS; lgkmcnt ordering only)
  uint4* rb = recbuf + wv * (16 * 9);
  if (kq < 3) {
    #pragma unroll
    for (int kk = 0; kk < 3; ++kk) {
      int k = kq * 3 + kk;
      float sy = jb[n * 36 + 2 * k]     + b_om[2 * k];
      float sx = jb[n * 36 + 2 * k + 1] + b_om[2 * k + 1];
      float sm = jb[n * 36 + 18 + k]    + b_om[18 + k];
      int pbase = ((b * Kn + k) * Hn + h) * Wn + w;
      float2 po = *(const float2*)(pre_offset + pbase * 2);
      float py = 10.f * tanhf(sy) + po.y + (float)(h - 1 + k / 3);
      float px = 10.f * tanhf(sx) + po.x + (float)(w - 1 + k % 3);
      float m  = 1.f / (1.f + expf(-sm * pre_sim[pbase]));
      float fy = floorf(py), fx = floorf(px);
      float dy = py - fy, dx = px - fx;
      int y0 = (int)fy, x0 = (int)fx;
      int y1 = y0 + 1, x1 = x0 + 1;
      bool vy0 = (y0 >= 0) & (y0 < Hn), vy1 = (y1 >= 0) & (y1 < Hn);
      bool vx0 = (x0 >= 0) & (x0 < Wn), vx1 = (x1 >= 0) & (x1 < Wn);
      unsigned r00 = (vy0 & vx0) ? (unsigned)(y0 * Wn + x0) : ZROW;
      unsigned r01 = (vy0 & vx1) ? (unsigned)(y0 * Wn + x1) : ZROW;
      unsigned r10 = (vy1 & vx0) ? (unsigned)(y1 * Wn + x0) : ZROW;
      unsigned r11 = (vy1 & vx1) ? (unsigned)(y1 * Wn + x1) : ZROW;
      float wy0 = 1.f - dy, wx0 = 1.f - dx;
      uint4 rec;
      rec.x = r00 | (r01 << 16);
      rec.y = r10 | (r11 << 16);
      rec.z = (unsigned)f2h(wy0 * wx0 * m) | ((unsigned)f2h(wy0 * dx * m) << 16);
      rec.w = (unsigned)f2h(dy * wx0 * m) | ((unsigned)f2h(dy * dx * m) << 16);
      rb[n * 9 + k] = rec;
    }
  }

  // ---- Phase 3: main GEMM (register-direct B-build, LDS-record reads)
  v4f acc0 = {0,0,0,0}, acc1 = {0,0,0,0}, acc2 = {0,0,0,0}, acc3 = {0,0,0,0};
  const unsigned short* xb = xT + b * XBSTRIDE;
  const v8s* Wf = (const v8s*)Wfrag;

  for (int k = 0; k < Kn; ++k) {
    uint4 rec = rb[n * 9 + k];              // ds_read_b128, 2-way = free
    float w00 = h2f(rec.z), w01 = h2f(rec.z >> 16);
    float w10 = h2f(rec.w), w11 = h2f(rec.w >> 16);
    unsigned o00 = (rec.x & 0xffff) * 64 + kq * 8;
    unsigned o01 = (rec.x >> 16)    * 64 + kq * 8;
    unsigned o10 = (rec.y & 0xffff) * 64 + kq * 8;
    unsigned o11 = (rec.y >> 16)    * 64 + kq * 8;

    const v8s* wk = Wf + (k * 8) * 64 + lane;

    #pragma unroll
    for (int half = 0; half < 2; ++half) {
      v8s c00 = *(const v8s*)(xb + o00 + half * 32);
      v8s c01 = *(const v8s*)(xb + o01 + half * 32);
      v8s c10 = *(const v8s*)(xb + o10 + half * 32);
      v8s c11 = *(const v8s*)(xb + o11 + half * 32);
      v8s Bf;
      #pragma unroll
      for (int j = 0; j < 8; ++j) {
        float s = fmaf(bf2f((unsigned short)c00[j]), w00,
                  fmaf(bf2f((unsigned short)c01[j]), w01,
                  fmaf(bf2f((unsigned short)c10[j]), w10,
                       bf2f((unsigned short)c11[j]) * w11)));
        Bf[j] = (short)f2bf(s);
      }
      v8s A0 = wk[(0 * 2 + half) * 64];
      v8s A1 = wk[(1 * 2 + half) * 64];
      v8s A2 = wk[(2 * 2 + half) * 64];
      v8s A3 = wk[(3 * 2 + half) * 64];
      acc0 = __builtin_amdgcn_mfma_f32_16x16x32_bf16(A0, Bf, acc0, 0, 0, 0);
      acc1 = __builtin_amdgcn_mfma_f32_16x16x32_bf16(A1, Bf, acc1, 0, 0, 0);
      acc2 = __builtin_amdgcn_mfma_f32_16x16x32_bf16(A2, Bf, acc2, 0, 0, 0);
      acc3 = __builtin_amdgcn_mfma_f32_16x16x32_bf16(A3, Bf, acc3, 0, 0, 0);
    }
  }

  // epilogue: D col=lane&15 (pix), row=kq*4+reg (o within 16-o tile)
  const float4* b4 = (const float4*)bias;
  float4 vb0 = b4[0 * 4 + kq], vb1 = b4[1 * 4 + kq];
  float4 vb2 = b4[2 * 4 + kq], vb3 = b4[3 * 4 + kq];
  float* ob = out + (b * On) * HWn + h * Wn + wq * 16 + n;
  #pragma unroll
  for (int reg = 0; reg < 4; ++reg) {
    ob[(0 * 16 + kq * 4 + reg) * HWn] = acc0[reg] + ((const float*)&vb0)[reg];
    ob[(1 * 16 + kq * 4 + reg) * HWn] = acc1[reg] + ((const float*)&vb1)[reg];
    ob[(2 * 16 + kq * 4 + reg) * HWn] = acc2[reg] + ((const float*)&vb2)[reg];
    ob[(3 * 16 + kq * 4 + reg) * HWn] = acc3[reg] + ((const float*)&vb3)[reg];
  }
}

extern "C" void kernel_launch(void* const* d_in, const int* in_sizes, int n_in,
                              void* d_out, int out_size, void* d_ws, size_t ws_size,
                              hipStream_t stream) {
  const float* x_main     = (const float*)d_in[0];
  const float* x_extra    = (const float*)d_in[1];
  const float* pre_offset = (const float*)d_in[2];
  const float* pre_sim    = (const float*)d_in[3];
  const float* weight     = (const float*)d_in[4];
  const float* bias       = (const float*)d_in[5];
  const float* w_om       = (const float*)d_in[6];
  const float* b_om       = (const float*)d_in[7];
  float* out = (float*)d_out;

  char* ws = (char*)d_ws;
  unsigned short* xT      = (unsigned short*)(ws);              //  8,389,120 B
  _Float16*       xeF     = (_Float16*)(ws + 8389120);          //  8,389,120 B
  unsigned short* Wfrag   = (unsigned short*)(ws + 16778240);   //     73,728 B
  _Float16*       WOMfrag = (_Float16*)(ws + 16851968);         //     36,864 B

  k_prep<<<2049, 256, 0, stream>>>(x_main, x_extra, weight, w_om,
                                   xT, xeF, Wfrag, WOMfrag);
  k_fused<<<1024, 256, 0, stream>>>(xT, xeF, Wfrag, WOMfrag,
                                    pre_offset, pre_sim, b_om, bias, out);
}

// Round 6
// 165.169 us; speedup vs baseline: 1.3372x; 1.0852x over previous
//
#include <hip/hip_runtime.h>
#include <math.h>

#define Bn 4
#define Cn 64
#define On 64
#define Hn 128
#define Wn 128
#define Kn 9
#define HWn (Hn*Wn)
#define ZROW 16384            // per-batch zero row index
#define XBSTRIDE (16385*64)   // per-batch stride (16384 rows + 1 zero row)

typedef short v8s __attribute__((ext_vector_type(8)));
typedef _Float16 v8h __attribute__((ext_vector_type(8)));
typedef float v4f __attribute__((ext_vector_type(4)));

__device__ inline unsigned short f2bf(float f) {
  unsigned u = __builtin_bit_cast(unsigned, f);
  u += 0x7fff + ((u >> 16) & 1);          // RNE
  return (unsigned short)(u >> 16);
}
__device__ inline float bf2f(unsigned short h) {
  unsigned u = ((unsigned)h) << 16;
  return __builtin_bit_cast(float, u);
}
__device__ inline unsigned short f2h(float f) {
  _Float16 h = (_Float16)f;
  return __builtin_bit_cast(unsigned short, h);
}
__device__ inline float h2f(unsigned v) {
  _Float16 h = __builtin_bit_cast(_Float16, (unsigned short)(v & 0xffff));
  return (float)h;
}

// ---------------------------------------------------------------------------
// K1 prep:
//   blk 0..1023   : x_main  NCHW fp32 -> xT  NHWC bf16 (64-px tiles)
//   blk 1024..2047: x_extra NCHW fp32 -> xeF NHWC f16
//   blk 2048..2111: weight repacks SPREAD over 64 blocks (kills serial tail)
// ---------------------------------------------------------------------------
__global__ __launch_bounds__(256) void k_prep(
    const float* __restrict__ x_main,
    const float* __restrict__ x_extra,
    const float* __restrict__ weight,
    const float* __restrict__ w_om,
    unsigned short* __restrict__ xT,
    _Float16* __restrict__ xeF,
    unsigned short* __restrict__ Wfrag,
    _Float16* __restrict__ WOMfrag)
{
  const int blk = blockIdx.x;
  const int t = threadIdx.x;
  const int lane = t & 63;
  const int grp = t >> 6;

  if (blk < 2048) {
    __shared__ float tile[64 * 65];
    int isExtra = blk >> 10;
    int b  = (blk >> 8) & 3;
    int p0 = (blk & 255) << 6;
    const float* src = (isExtra ? x_extra : x_main) + b * Cn * HWn + p0;
    #pragma unroll
    for (int i = 0; i < 16; ++i) {
      int c = i * 4 + grp;
      tile[c * 65 + lane] = src[c * HWn + lane];     // 256B coalesced
    }
    __syncthreads();
    if (!isExtra) {
      unsigned short* dst = xT + b * XBSTRIDE + p0 * 64;
      #pragma unroll
      for (int i = 0; i < 16; ++i) {
        int p = i * 4 + grp;
        dst[p * 64 + lane] = f2bf(tile[lane * 65 + p]);   // stride65: no conflict
      }
    } else {
      _Float16* dst = xeF + b * XBSTRIDE + p0 * 64;
      #pragma unroll
      for (int i = 0; i < 16; ++i) {
        int p = i * 4 + grp;
        dst[p * 64 + lane] = (_Float16)tile[lane * 65 + p];
      }
    }
  } else {
    int rb = blk - 2048;   // 0..63
    // main-GEMM weights: A[o=ot*16+(ln&15)][c=hk*32+(ln>>4)*8+j] for (k,ot,hk)
    for (int idx = rb * 256 + t; idx < 36864; idx += 64 * 256) {
      int j  = idx & 7;
      int ln = (idx >> 3) & 63;
      int hk = (idx >> 9) & 1;
      int ot = (idx >> 10) & 3;
      int k  = idx >> 12;
      int o = ot * 16 + (ln & 15);
      int c = hk * 32 + (ln >> 4) * 8 + j;
      Wfrag[idx] = f2bf(weight[(o * Cn + c) * Kn + k]);
    }
    // conv weights: order (k9, half, jt, lane, j); j-rows 27..31 zero
    for (int idx = rb * 256 + t; idx < 18432; idx += 64 * 256) {
      int j    = idx & 7;
      int ln   = (idx >> 3) & 63;
      int jt   = (idx >> 9) & 1;
      int half = (idx >> 10) & 1;
      int k9   = idx >> 11;
      int jo = jt * 16 + (ln & 15);
      int c  = half * 32 + (ln >> 4) * 8 + j;
      float v = (jo < 27) ? w_om[(jo * Cn + c) * Kn + k9] : 0.f;
      WOMfrag[idx] = (_Float16)v;
    }
    if (rb == 0 && t < 256) {
      int b = t >> 6, c = t & 63;
      xT[b * XBSTRIDE + ZROW * 64 + c] = 0;
      xeF[b * XBSTRIDE + ZROW * 64 + c] = (_Float16)0.f;
    }
  }
}

// ---------------------------------------------------------------------------
// K2 fused: block = 128 threads = 2 waves on the SAME 16 pixels, K-split.
//   Phase 1: conv (mfma 16x16x32 f16), c-split: wave w does c[w*32,+32) ->
//            partial j-sums to LDS, 1 barrier.
//   Phase 2: wave w builds gather records for its k-range (w0: k0..4,
//            w1: k5..8) reading both partials; writes to own LDS region
//            (no barrier needed before phase 3 — within-wave ordering).
//   Phase 3: main GEMM, wave w accumulates its k-range; wave1 dumps acc to
//            LDS, 1 barrier, wave0 reduces + bias + store.
// Grid 4096 x 128thr = 32 waves/CU (8/SIMD) for latency hiding.
// ---------------------------------------------------------------------------
template <int KCNT>
__device__ inline void gemm_part(
    const unsigned short* __restrict__ xb,
    const v8s* __restrict__ Wf,
    const uint4* __restrict__ rb_w,
    int k0, int n, int kq, int lane,
    v4f& acc0, v4f& acc1, v4f& acc2, v4f& acc3)
{
  #pragma unroll
  for (int kk = 0; kk < KCNT; ++kk) {
    uint4 rec = rb_w[n * 5 + kk];
    int k = k0 + kk;
    float w00 = h2f(rec.z), w01 = h2f(rec.z >> 16);
    float w10 = h2f(rec.w), w11 = h2f(rec.w >> 16);
    unsigned o00 = (rec.x & 0xffff) * 64 + kq * 8;
    unsigned o01 = (rec.x >> 16)    * 64 + kq * 8;
    unsigned o10 = (rec.y & 0xffff) * 64 + kq * 8;
    unsigned o11 = (rec.y >> 16)    * 64 + kq * 8;
    const v8s* wk = Wf + (k * 8) * 64 + lane;
    #pragma unroll
    for (int half = 0; half < 2; ++half) {
      v8s c00 = *(const v8s*)(xb + o00 + half * 32);
      v8s c01 = *(const v8s*)(xb + o01 + half * 32);
      v8s c10 = *(const v8s*)(xb + o10 + half * 32);
      v8s c11 = *(const v8s*)(xb + o11 + half * 32);
      v8s Bf;
      #pragma unroll
      for (int j = 0; j < 8; ++j) {
        float s = fmaf(bf2f((unsigned short)c00[j]), w00,
                  fmaf(bf2f((unsigned short)c01[j]), w01,
                  fmaf(bf2f((unsigned short)c10[j]), w10,
                       bf2f((unsigned short)c11[j]) * w11)));
        Bf[j] = (short)f2bf(s);
      }
      v8s A0 = wk[(0 * 2 + half) * 64];
      v8s A1 = wk[(1 * 2 + half) * 64];
      v8s A2 = wk[(2 * 2 + half) * 64];
      v8s A3 = wk[(3 * 2 + half) * 64];
      acc0 = __builtin_amdgcn_mfma_f32_16x16x32_bf16(A0, Bf, acc0, 0, 0, 0);
      acc1 = __builtin_amdgcn_mfma_f32_16x16x32_bf16(A1, Bf, acc1, 0, 0, 0);
      acc2 = __builtin_amdgcn_mfma_f32_16x16x32_bf16(A2, Bf, acc2, 0, 0, 0);
      acc3 = __builtin_amdgcn_mfma_f32_16x16x32_bf16(A3, Bf, acc3, 0, 0, 0);
    }
  }
}

__global__ __launch_bounds__(128, 8) void k_fused(
    const unsigned short* __restrict__ xT,
    const _Float16* __restrict__ xeF,
    const unsigned short* __restrict__ Wfrag,
    const _Float16* __restrict__ WOMfrag,
    const float* __restrict__ pre_offset,
    const float* __restrict__ pre_sim,
    const float* __restrict__ b_om,
    const float* __restrict__ bias,
    float* __restrict__ out)
{
  // layout: [0..575] jpart wave0, [576..1151] jpart wave1 (aliased by accred),
  //         [1152..1791] records (2 waves x 16px x 5 recs x 4 dwords)
  __shared__ float smem[1792];

  const int t    = threadIdx.x;
  const int lane = t & 63;
  const int wv   = __builtin_amdgcn_readfirstlane(t >> 6);
  const int blk  = blockIdx.x;
  const int b    = blk >> 10;
  const int h    = (blk >> 3) & 127;
  const int wq   = blk & 7;              // 16-pixel group (0..7)
  const int kq   = lane >> 4;
  const int n    = lane & 15;
  const int w    = wq * 16 + n;

  // ---- Phase 1: conv partials on MFMA, c-half = wv
  unsigned tapoff[9];
  #pragma unroll
  for (int k9 = 0; k9 < 9; ++k9) {
    int r  = h - 1 + k9 / 3;
    int cc = w - 1 + k9 % 3;
    bool v = ((unsigned)r < (unsigned)Hn) & ((unsigned)cc < (unsigned)Wn);
    tapoff[k9] = (v ? (unsigned)(r * Wn + cc) : (unsigned)ZROW) * 64u;
  }

  const _Float16* xe = xeF + b * XBSTRIDE;
  const v8h* Wom = (const v8h*)WOMfrag;
  v4f ca0 = {0,0,0,0}, ca1 = {0,0,0,0};
  #pragma unroll
  for (int k9 = 0; k9 < 9; ++k9) {
    int abase = ((k9 * 2 + wv) * 2) * 64 + lane;
    v8h A0 = Wom[abase];
    v8h A1 = Wom[abase + 64];
    v8h Bt = *(const v8h*)(xe + tapoff[k9] + wv * 32 + kq * 8);
    ca0 = __builtin_amdgcn_mfma_f32_16x16x32_f16(A0, Bt, ca0, 0, 0, 0);
    ca1 = __builtin_amdgcn_mfma_f32_16x16x32_f16(A1, Bt, ca1, 0, 0, 0);
  }

  // partial j-sums: D col=n (pixel), row=kq*4+reg (j)
  float* jp = smem + wv * 576;
  *(v4f*)(jp + n * 36 + kq * 4)      = ca0;
  *(v4f*)(jp + n * 36 + 16 + kq * 4) = ca1;
  __syncthreads();   // barrier 1

  // ---- Phase 2: records for this wave's k-range
  const int k0   = wv ? 5 : 0;
  const int kcnt = wv ? 4 : 5;
  uint4* rb_w = (uint4*)(smem + 1152) + wv * (16 * 5);
  const float* jp0 = smem;
  const float* jp1 = smem + 576;
  for (int kk = kq; kk < kcnt; kk += 4) {
    int k = k0 + kk;
    float sy = jp0[n * 36 + 2 * k]     + jp1[n * 36 + 2 * k]     + b_om[2 * k];
    float sx = jp0[n * 36 + 2 * k + 1] + jp1[n * 36 + 2 * k + 1] + b_om[2 * k + 1];
    float sm = jp0[n * 36 + 18 + k]    + jp1[n * 36 + 18 + k]    + b_om[18 + k];
    int pbase = ((b * Kn + k) * Hn + h) * Wn + w;
    float2 po = *(const float2*)(pre_offset + pbase * 2);
    float py = 10.f * tanhf(sy) + po.y + (float)(h - 1 + k / 3);
    float px = 10.f * tanhf(sx) + po.x + (float)(w - 1 + k % 3);
    float m  = 1.f / (1.f + expf(-sm * pre_sim[pbase]));
    float fy = floorf(py), fx = floorf(px);
    float dy = py - fy, dx = px - fx;
    int y0 = (int)fy, x0 = (int)fx;
    int y1 = y0 + 1, x1 = x0 + 1;
    bool vy0 = (y0 >= 0) & (y0 < Hn), vy1 = (y1 >= 0) & (y1 < Hn);
    bool vx0 = (x0 >= 0) & (x0 < Wn), vx1 = (x1 >= 0) & (x1 < Wn);
    unsigned r00 = (vy0 & vx0) ? (unsigned)(y0 * Wn + x0) : ZROW;
    unsigned r01 = (vy0 & vx1) ? (unsigned)(y0 * Wn + x1) : ZROW;
    unsigned r10 = (vy1 & vx0) ? (unsigned)(y1 * Wn + x0) : ZROW;
    unsigned r11 = (vy1 & vx1) ? (unsigned)(y1 * Wn + x1) : ZROW;
    float wy0 = 1.f - dy, wx0 = 1.f - dx;
    uint4 rec;
    rec.x = r00 | (r01 << 16);
    rec.y = r10 | (r11 << 16);
    rec.z = (unsigned)f2h(wy0 * wx0 * m) | ((unsigned)f2h(wy0 * dx * m) << 16);
    rec.w = (unsigned)f2h(dy * wx0 * m) | ((unsigned)f2h(dy * dx * m) << 16);
    rb_w[n * 5 + kk] = rec;
  }
  // no barrier: phase 3 reads only this wave's own records (lgkmcnt ordering)

  // ---- Phase 3: main GEMM over this wave's k-range
  v4f acc0 = {0,0,0,0}, acc1 = {0,0,0,0}, acc2 = {0,0,0,0}, acc3 = {0,0,0,0};
  const unsigned short* xb = xT + b * XBSTRIDE;
  const v8s* Wf = (const v8s*)Wfrag;
  if (wv == 0)
    gemm_part<5>(xb, Wf, rb_w, 0, n, kq, lane, acc0, acc1, acc2, acc3);
  else
    gemm_part<4>(xb, Wf, rb_w, 5, n, kq, lane, acc0, acc1, acc2, acc3);

  // ---- reduce: wave1 dumps acc (reuses jpart region), wave0 adds+stores
  float* sred = smem;           // 1024 floats, aliases jpart (dead now)
  if (wv == 1) {
    #pragma unroll
    for (int reg = 0; reg < 4; ++reg) {
      sred[(0 * 4 + reg) * 64 + lane]  = acc0[reg];
      sred[(1 * 4 + reg) * 64 + lane]  = acc1[reg];
      sred[(2 * 4 + reg) * 64 + lane]  = acc2[reg];
      sred[(3 * 4 + reg) * 64 + lane]  = acc3[reg];
    }
  }
  __syncthreads();   // barrier 2
  if (wv == 0) {
    const float4* b4 = (const float4*)bias;
    float4 vb0 = b4[0 * 4 + kq], vb1 = b4[1 * 4 + kq];
    float4 vb2 = b4[2 * 4 + kq], vb3 = b4[3 * 4 + kq];
    float* ob = out + (b * On) * HWn + h * Wn + wq * 16 + n;
    #pragma unroll
    for (int reg = 0; reg < 4; ++reg) {
      ob[(0 * 16 + kq * 4 + reg) * HWn] =
          acc0[reg] + sred[(0 * 4 + reg) * 64 + lane] + ((const float*)&vb0)[reg];
      ob[(1 * 16 + kq * 4 + reg) * HWn] =
          acc1[reg] + sred[(1 * 4 + reg) * 64 + lane] + ((const float*)&vb1)[reg];
      ob[(2 * 16 + kq * 4 + reg) * HWn] =
          acc2[reg] + sred[(2 * 4 + reg) * 64 + lane] + ((const float*)&vb2)[reg];
      ob[(3 * 16 + kq * 4 + reg) * HWn] =
          acc3[reg] + sred[(3 * 4 + reg) * 64 + lane] + ((const float*)&vb3)[reg];
    }
  }
}

extern "C" void kernel_launch(void* const* d_in, const int* in_sizes, int n_in,
                              void* d_out, int out_size, void* d_ws, size_t ws_size,
                              hipStream_t stream) {
  const float* x_main     = (const float*)d_in[0];
  const float* x_extra    = (const float*)d_in[1];
  const float* pre_offset = (const float*)d_in[2];
  const float* pre_sim    = (const float*)d_in[3];
  const float* weight     = (const float*)d_in[4];
  const float* bias       = (const float*)d_in[5];
  const float* w_om       = (const float*)d_in[6];
  const float* b_om       = (const float*)d_in[7];
  float* out = (float*)d_out;

  char* ws = (char*)d_ws;
  unsigned short* xT      = (unsigned short*)(ws);              //  8,389,120 B
  _Float16*       xeF     = (_Float16*)(ws + 8389120);          //  8,389,120 B
  unsigned short* Wfrag   = (unsigned short*)(ws + 16778240);   //     73,728 B
  _Float16*       WOMfrag = (_Float16*)(ws + 16851968);         //     36,864 B

  k_prep<<<2112, 256, 0, stream>>>(x_main, x_extra, weight, w_om,
                                   xT, xeF, Wfrag, WOMfrag);
  k_fused<<<4096, 128, 0, stream>>>(xT, xeF, Wfrag, WOMfrag,
                                    pre_offset, pre_sim, b_om, bias, out);
}

// Round 7
// 154.815 us; speedup vs baseline: 1.4267x; 1.0669x over previous
//
#include <hip/hip_runtime.h>
#include <math.h>

#define Bn 4
#define Cn 64
#define On 64
#define Hn 128
#define Wn 128
#define Kn 9
#define HWn (Hn*Wn)
#define ZROW 16384            // per-batch zero row index
#define XBSTRIDE (16385*64)   // per-batch stride (16384 rows + 1 zero row)

typedef short v8s __attribute__((ext_vector_type(8)));
typedef _Float16 v8h __attribute__((ext_vector_type(8)));
typedef float v4f __attribute__((ext_vector_type(4)));

__device__ inline unsigned short f2bf(float f) {
  unsigned u = __builtin_bit_cast(unsigned, f);
  u += 0x7fff + ((u >> 16) & 1);          // RNE
  return (unsigned short)(u >> 16);
}
__device__ inline float bf2f(unsigned short h) {
  unsigned u = ((unsigned)h) << 16;
  return __builtin_bit_cast(float, u);
}
__device__ inline unsigned short f2h(float f) {
  _Float16 h = (_Float16)f;
  return __builtin_bit_cast(unsigned short, h);
}
__device__ inline float h2f(unsigned v) {
  _Float16 h = __builtin_bit_cast(_Float16, (unsigned short)(v & 0xffff));
  return (float)h;
}

// ---------------------------------------------------------------------------
// K1 prep:
//   blk 0..1023   : x_main  NCHW fp32 -> xT  NHWC bf16 (64-px tiles)
//   blk 1024..2047: x_extra NCHW fp32 -> xeF NHWC f16
//   blk 2048..2111: weight repacks spread over 64 blocks
// ---------------------------------------------------------------------------
__global__ __launch_bounds__(256) void k_prep(
    const float* __restrict__ x_main,
    const float* __restrict__ x_extra,
    const float* __restrict__ weight,
    const float* __restrict__ w_om,
    unsigned short* __restrict__ xT,
    _Float16* __restrict__ xeF,
    unsigned short* __restrict__ Wfrag,
    _Float16* __restrict__ WOMfrag)
{
  const int blk = blockIdx.x;
  const int t = threadIdx.x;
  const int lane = t & 63;
  const int grp = t >> 6;

  if (blk < 2048) {
    __shared__ float tile[64 * 65];
    int isExtra = blk >> 10;
    int b  = (blk >> 8) & 3;
    int p0 = (blk & 255) << 6;
    const float* src = (isExtra ? x_extra : x_main) + b * Cn * HWn + p0;
    #pragma unroll
    for (int i = 0; i < 16; ++i) {
      int c = i * 4 + grp;
      tile[c * 65 + lane] = src[c * HWn + lane];     // 256B coalesced
    }
    __syncthreads();
    if (!isExtra) {
      unsigned short* dst = xT + b * XBSTRIDE + p0 * 64;
      #pragma unroll
      for (int i = 0; i < 16; ++i) {
        int p = i * 4 + grp;
        dst[p * 64 + lane] = f2bf(tile[lane * 65 + p]);   // stride65: no conflict
      }
    } else {
      _Float16* dst = xeF + b * XBSTRIDE + p0 * 64;
      #pragma unroll
      for (int i = 0; i < 16; ++i) {
        int p = i * 4 + grp;
        dst[p * 64 + lane] = (_Float16)tile[lane * 65 + p];
      }
    }
  } else {
    int rb = blk - 2048;   // 0..63
    // main-GEMM weights: A[o=ot*16+(ln&15)][c=hk*32+(ln>>4)*8+j] for (k,ot,hk)
    for (int idx = rb * 256 + t; idx < 36864; idx += 64 * 256) {
      int j  = idx & 7;
      int ln = (idx >> 3) & 63;
      int hk = (idx >> 9) & 1;
      int ot = (idx >> 10) & 3;
      int k  = idx >> 12;
      int o = ot * 16 + (ln & 15);
      int c = hk * 32 + (ln >> 4) * 8 + j;
      Wfrag[idx] = f2bf(weight[(o * Cn + c) * Kn + k]);
    }
    // conv weights: order (k9, half, jt, lane, j); j-rows 27..31 zero
    for (int idx = rb * 256 + t; idx < 18432; idx += 64 * 256) {
      int j    = idx & 7;
      int ln   = (idx >> 3) & 63;
      int jt   = (idx >> 9) & 1;
      int half = (idx >> 10) & 1;
      int k9   = idx >> 11;
      int jo = jt * 16 + (ln & 15);
      int c  = half * 32 + (ln >> 4) * 8 + j;
      float v = (jo < 27) ? w_om[(jo * Cn + c) * Kn + k9] : 0.f;
      WOMfrag[idx] = (_Float16)v;
    }
    if (rb == 0 && t < 256) {
      int b = t >> 6, c = t & 63;
      xT[b * XBSTRIDE + ZROW * 64 + c] = 0;
      xeF[b * XBSTRIDE + ZROW * 64 + c] = (_Float16)0.f;
    }
  }
}

// ---------------------------------------------------------------------------
// K2 fused, barrier-free (round-5 shape + software-pipelined k-loop).
// Block = (b, h, 64 contiguous w's), wave = 16 pixels, full K per wave.
// Phase 1: conv via mfma 16x16x32 f16 -> 27 j-values/pixel (per-wave LDS).
// Phase 2: per-wave gather-record build (per-wave LDS, no barrier).
// Phase 3: main GEMM, prefetching k+1 record + half0 corners during k.
// ---------------------------------------------------------------------------
__global__ __launch_bounds__(256, 4) void k_fused(
    const unsigned short* __restrict__ xT,
    const _Float16* __restrict__ xeF,
    const unsigned short* __restrict__ Wfrag,
    const _Float16* __restrict__ WOMfrag,
    const float* __restrict__ pre_offset,
    const float* __restrict__ pre_sim,
    const float* __restrict__ b_om,
    const float* __restrict__ bias,
    float* __restrict__ out)
{
  __shared__ float jbuf[4 * 16 * 36];    // per-wave j-values, stride 36
  __shared__ uint4 recbuf[4 * 16 * 9];   // per-wave gather records

  const int t    = threadIdx.x;
  const int lane = t & 63;
  const int wv   = __builtin_amdgcn_readfirstlane(t >> 6);
  const int blk  = blockIdx.x;
  const int b    = blk >> 8;
  const int h    = (blk >> 1) & 127;
  const int wq   = (blk & 1) * 4 + wv;   // 16-pixel group (0..7)
  const int kq   = lane >> 4;            // c-subgroup / j-subgroup
  const int n    = lane & 15;            // pixel within tile
  const int w    = wq * 16 + n;

  // ---- Phase 1: offset conv on MFMA
  unsigned tapoff[9];
  #pragma unroll
  for (int k9 = 0; k9 < 9; ++k9) {
    int r  = h - 1 + k9 / 3;
    int cc = w - 1 + k9 % 3;
    bool v = ((unsigned)r < (unsigned)Hn) & ((unsigned)cc < (unsigned)Wn);
    tapoff[k9] = (v ? (unsigned)(r * Wn + cc) : (unsigned)ZROW) * 64u;
  }

  const _Float16* xe = xeF + b * XBSTRIDE;
  const v8h* Wom = (const v8h*)WOMfrag;
  v4f ca0 = {0,0,0,0}, ca1 = {0,0,0,0};
  for (int k9 = 0; k9 < 9; ++k9) {
    #pragma unroll
    for (int half = 0; half < 2; ++half) {
      int abase = ((k9 * 2 + half) * 2) * 64 + lane;
      v8h A0 = Wom[abase];
      v8h A1 = Wom[abase + 64];
      v8h Bt = *(const v8h*)(xe + tapoff[k9] + half * 32 + kq * 8);
      ca0 = __builtin_amdgcn_mfma_f32_16x16x32_f16(A0, Bt, ca0, 0, 0, 0);
      ca1 = __builtin_amdgcn_mfma_f32_16x16x32_f16(A1, Bt, ca1, 0, 0, 0);
    }
  }

  // D: col=lane&15 (pixel), row=kq*4+reg (j). Stride-36 rows: 2-way = free.
  float* jb = jbuf + wv * (16 * 36);
  *(v4f*)(jb + n * 36 + kq * 4)      = ca0;   // j 0..15
  *(v4f*)(jb + n * 36 + 16 + kq * 4) = ca1;   // j 16..31

  // ---- Phase 2: records (same wave reads its own LDS; lgkmcnt ordering only)
  uint4* rb = recbuf + wv * (16 * 9);
  if (kq < 3) {
    #pragma unroll
    for (int kk = 0; kk < 3; ++kk) {
      int k = kq * 3 + kk;
      float sy = jb[n * 36 + 2 * k]     + b_om[2 * k];
      float sx = jb[n * 36 + 2 * k + 1] + b_om[2 * k + 1];
      float sm = jb[n * 36 + 18 + k]    + b_om[18 + k];
      int pbase = ((b * Kn + k) * Hn + h) * Wn + w;
      float2 po = *(const float2*)(pre_offset + pbase * 2);
      float py = 10.f * tanhf(sy) + po.y + (float)(h - 1 + k / 3);
      float px = 10.f * tanhf(sx) + po.x + (float)(w - 1 + k % 3);
      float m  = 1.f / (1.f + expf(-sm * pre_sim[pbase]));
      float fy = floorf(py), fx = floorf(px);
      float dy = py - fy, dx = px - fx;
      int y0 = (int)fy, x0 = (int)fx;
      int y1 = y0 + 1, x1 = x0 + 1;
      bool vy0 = (y0 >= 0) & (y0 < Hn), vy1 = (y1 >= 0) & (y1 < Hn);
      bool vx0 = (x0 >= 0) & (x0 < Wn), vx1 = (x1 >= 0) & (x1 < Wn);
      unsigned r00 = (vy0 & vx0) ? (unsigned)(y0 * Wn + x0) : ZROW;
      unsigned r01 = (vy0 & vx1) ? (unsigned)(y0 * Wn + x1) : ZROW;
      unsigned r10 = (vy1 & vx0) ? (unsigned)(y1 * Wn + x0) : ZROW;
      unsigned r11 = (vy1 & vx1) ? (unsigned)(y1 * Wn + x1) : ZROW;
      float wy0 = 1.f - dy, wx0 = 1.f - dx;
      uint4 rec;
      rec.x = r00 | (r01 << 16);
      rec.y = r10 | (r11 << 16);
      rec.z = (unsigned)f2h(wy0 * wx0 * m) | ((unsigned)f2h(wy0 * dx * m) << 16);
      rec.w = (unsigned)f2h(dy * wx0 * m) | ((unsigned)f2h(dy * dx * m) << 16);
      rb[n * 9 + k] = rec;
    }
  }

  // ---- Phase 3: main GEMM, software-pipelined over k
  v4f acc0 = {0,0,0,0}, acc1 = {0,0,0,0}, acc2 = {0,0,0,0}, acc3 = {0,0,0,0};
  const unsigned short* xb = xT + b * XBSTRIDE;
  const v8s* Wf = (const v8s*)Wfrag;

  // preload k=0: record, offsets, half0 corners
  uint4 rec0 = rb[n * 9 + 0];
  float w00 = h2f(rec0.z), w01 = h2f(rec0.z >> 16);
  float w10 = h2f(rec0.w), w11 = h2f(rec0.w >> 16);
  unsigned o00 = (rec0.x & 0xffff) * 64 + kq * 8;
  unsigned o01 = (rec0.x >> 16)    * 64 + kq * 8;
  unsigned o10 = (rec0.y & 0xffff) * 64 + kq * 8;
  unsigned o11 = (rec0.y >> 16)    * 64 + kq * 8;
  v8s C0 = *(const v8s*)(xb + o00);
  v8s C1 = *(const v8s*)(xb + o01);
  v8s C2 = *(const v8s*)(xb + o10);
  v8s C3 = *(const v8s*)(xb + o11);

  #pragma unroll
  for (int k = 0; k < 9; ++k) {
    // half1 corners: same 128B lines as half0 (warm) — issue first
    v8s H0 = *(const v8s*)(xb + o00 + 32);
    v8s H1 = *(const v8s*)(xb + o01 + 32);
    v8s H2 = *(const v8s*)(xb + o10 + 32);
    v8s H3 = *(const v8s*)(xb + o11 + 32);

    // A-fragments for k (L2-hot): used ~90 instrs later at the MFMAs
    const v8s* wk = Wf + (k * 8) * 64 + lane;
    v8s A0 = wk[0 * 64], A1 = wk[1 * 64], A2 = wk[2 * 64], A3 = wk[3 * 64];
    v8s A4 = wk[4 * 64], A5 = wk[5 * 64], A6 = wk[6 * 64], A7 = wk[7 * 64];

    // prefetch k+1: record + half0 corners (these cover the latency of k+1)
    v8s N0, N1, N2, N3;
    float nw00 = 0.f, nw01 = 0.f, nw10 = 0.f, nw11 = 0.f;
    unsigned p00 = 0, p01 = 0, p10 = 0, p11 = 0;
    if (k < 8) {
      uint4 rn = rb[n * 9 + k + 1];
      nw00 = h2f(rn.z); nw01 = h2f(rn.z >> 16);
      nw10 = h2f(rn.w); nw11 = h2f(rn.w >> 16);
      p00 = (rn.x & 0xffff) * 64 + kq * 8;
      p01 = (rn.x >> 16)    * 64 + kq * 8;
      p10 = (rn.y & 0xffff) * 64 + kq * 8;
      p11 = (rn.y >> 16)    * 64 + kq * 8;
      N0 = *(const v8s*)(xb + p00);
      N1 = *(const v8s*)(xb + p01);
      N2 = *(const v8s*)(xb + p10);
      N3 = *(const v8s*)(xb + p11);
    }

    // interp half0 (C arrived via prev-iter prefetch) then half1
    v8s Bf0, Bf1;
    #pragma unroll
    for (int j = 0; j < 8; ++j) {
      float s = fmaf(bf2f((unsigned short)C0[j]), w00,
                fmaf(bf2f((unsigned short)C1[j]), w01,
                fmaf(bf2f((unsigned short)C2[j]), w10,
                     bf2f((unsigned short)C3[j]) * w11)));
      Bf0[j] = (short)f2bf(s);
    }
    #pragma unroll
    for (int j = 0; j < 8; ++j) {
      float s = fmaf(bf2f((unsigned short)H0[j]), w00,
                fmaf(bf2f((unsigned short)H1[j]), w01,
                fmaf(bf2f((unsigned short)H2[j]), w10,
                     bf2f((unsigned short)H3[j]) * w11)));
      Bf1[j] = (short)f2bf(s);
    }

    // MFMA: half0 uses A{0,2,4,6}, half1 uses A{1,3,5,7}
    acc0 = __builtin_amdgcn_mfma_f32_16x16x32_bf16(A0, Bf0, acc0, 0, 0, 0);
    acc1 = __builtin_amdgcn_mfma_f32_16x16x32_bf16(A2, Bf0, acc1, 0, 0, 0);
    acc2 = __builtin_amdgcn_mfma_f32_16x16x32_bf16(A4, Bf0, acc2, 0, 0, 0);
    acc3 = __builtin_amdgcn_mfma_f32_16x16x32_bf16(A6, Bf0, acc3, 0, 0, 0);
    acc0 = __builtin_amdgcn_mfma_f32_16x16x32_bf16(A1, Bf1, acc0, 0, 0, 0);
    acc1 = __builtin_amdgcn_mfma_f32_16x16x32_bf16(A3, Bf1, acc1, 0, 0, 0);
    acc2 = __builtin_amdgcn_mfma_f32_16x16x32_bf16(A5, Bf1, acc2, 0, 0, 0);
    acc3 = __builtin_amdgcn_mfma_f32_16x16x32_bf16(A7, Bf1, acc3, 0, 0, 0);

    // rotate pipeline state
    if (k < 8) {
      C0 = N0; C1 = N1; C2 = N2; C3 = N3;
      w00 = nw00; w01 = nw01; w10 = nw10; w11 = nw11;
      o00 = p00; o01 = p01; o10 = p10; o11 = p11;
    }
  }

  // epilogue: D col=lane&15 (pix), row=kq*4+reg (o within 16-o tile)
  const float4* b4 = (const float4*)bias;
  float4 vb0 = b4[0 * 4 + kq], vb1 = b4[1 * 4 + kq];
  float4 vb2 = b4[2 * 4 + kq], vb3 = b4[3 * 4 + kq];
  float* ob = out + (b * On) * HWn + h * Wn + wq * 16 + n;
  #pragma unroll
  for (int reg = 0; reg < 4; ++reg) {
    ob[(0 * 16 + kq * 4 + reg) * HWn] = acc0[reg] + ((const float*)&vb0)[reg];
    ob[(1 * 16 + kq * 4 + reg) * HWn] = acc1[reg] + ((const float*)&vb1)[reg];
    ob[(2 * 16 + kq * 4 + reg) * HWn] = acc2[reg] + ((const float*)&vb2)[reg];
    ob[(3 * 16 + kq * 4 + reg) * HWn] = acc3[reg] + ((const float*)&vb3)[reg];
  }
}

extern "C" void kernel_launch(void* const* d_in, const int* in_sizes, int n_in,
                              void* d_out, int out_size, void* d_ws, size_t ws_size,
                              hipStream_t stream) {
  const float* x_main     = (const float*)d_in[0];
  const float* x_extra    = (const float*)d_in[1];
  const float* pre_offset = (const float*)d_in[2];
  const float* pre_sim    = (const float*)d_in[3];
  const float* weight     = (const float*)d_in[4];
  const float* bias       = (const float*)d_in[5];
  const float* w_om       = (const float*)d_in[6];
  const float* b_om       = (const float*)d_in[7];
  float* out = (float*)d_out;

  char* ws = (char*)d_ws;
  unsigned short* xT      = (unsigned short*)(ws);              //  8,389,120 B
  _Float16*       xeF     = (_Float16*)(ws + 8389120);          //  8,389,120 B
  unsigned short* Wfrag   = (unsigned short*)(ws + 16778240);   //     73,728 B
  _Float16*       WOMfrag = (_Float16*)(ws + 16851968);         //     36,864 B

  k_prep<<<2112, 256, 0, stream>>>(x_main, x_extra, weight, w_om,
                                   xT, xeF, Wfrag, WOMfrag);
  k_fused<<<1024, 256, 0, stream>>>(xT, xeF, Wfrag, WOMfrag,
                                    pre_offset, pre_sim, b_om, bias, out);
}

// Round 8
// 149.962 us; speedup vs baseline: 1.4728x; 1.0324x over previous
//
#include <hip/hip_runtime.h>
#include <math.h>

#define Bn 4
#define Cn 64
#define On 64
#define Hn 128
#define Wn 128
#define Kn 9
#define HWn (Hn*Wn)
#define ZROW 16384            // per-batch zero row index
#define XBSTRIDE (16385*64)   // per-batch stride (16384 rows + 1 zero row)

typedef short v8s __attribute__((ext_vector_type(8)));
typedef _Float16 v8h __attribute__((ext_vector_type(8)));
typedef float v4f __attribute__((ext_vector_type(4)));

__device__ inline unsigned short f2bf(float f) {
  unsigned u = __builtin_bit_cast(unsigned, f);
  u += 0x7fff + ((u >> 16) & 1);          // RNE
  return (unsigned short)(u >> 16);
}
__device__ inline float bf2f(unsigned short h) {
  unsigned u = ((unsigned)h) << 16;
  return __builtin_bit_cast(float, u);
}
__device__ inline unsigned short f2h(float f) {
  _Float16 h = (_Float16)f;
  return __builtin_bit_cast(unsigned short, h);
}
__device__ inline float h2f(unsigned v) {
  _Float16 h = __builtin_bit_cast(_Float16, (unsigned short)(v & 0xffff));
  return (float)h;
}

// ---------------------------------------------------------------------------
// K1 prep:
//   blk 0..1023   : x_main  NCHW fp32 -> xT  NHWC bf16 (64-px tiles)
//   blk 1024..2047: x_extra NCHW fp32 -> xeF NHWC f16
//   blk 2048..2111: weight repacks spread over 64 blocks
// ---------------------------------------------------------------------------
__global__ __launch_bounds__(256) void k_prep(
    const float* __restrict__ x_main,
    const float* __restrict__ x_extra,
    const float* __restrict__ weight,
    const float* __restrict__ w_om,
    unsigned short* __restrict__ xT,
    _Float16* __restrict__ xeF,
    unsigned short* __restrict__ Wfrag,
    _Float16* __restrict__ WOMfrag)
{
  const int blk = blockIdx.x;
  const int t = threadIdx.x;
  const int lane = t & 63;
  const int grp = t >> 6;

  if (blk < 2048) {
    __shared__ float tile[64 * 65];
    int isExtra = blk >> 10;
    int b  = (blk >> 8) & 3;
    int p0 = (blk & 255) << 6;
    const float* src = (isExtra ? x_extra : x_main) + b * Cn * HWn + p0;
    #pragma unroll
    for (int i = 0; i < 16; ++i) {
      int c = i * 4 + grp;
      tile[c * 65 + lane] = src[c * HWn + lane];     // 256B coalesced
    }
    __syncthreads();
    if (!isExtra) {
      unsigned short* dst = xT + b * XBSTRIDE + p0 * 64;
      #pragma unroll
      for (int i = 0; i < 16; ++i) {
        int p = i * 4 + grp;
        dst[p * 64 + lane] = f2bf(tile[lane * 65 + p]);   // stride65: no conflict
      }
    } else {
      _Float16* dst = xeF + b * XBSTRIDE + p0 * 64;
      #pragma unroll
      for (int i = 0; i < 16; ++i) {
        int p = i * 4 + grp;
        dst[p * 64 + lane] = (_Float16)tile[lane * 65 + p];
      }
    }
  } else {
    int rb = blk - 2048;   // 0..63
    // main-GEMM weights: A[o=ot*16+(ln&15)][c=hk*32+(ln>>4)*8+j] for (k,ot,hk)
    for (int idx = rb * 256 + t; idx < 36864; idx += 64 * 256) {
      int j  = idx & 7;
      int ln = (idx >> 3) & 63;
      int hk = (idx >> 9) & 1;
      int ot = (idx >> 10) & 3;
      int k  = idx >> 12;
      int o = ot * 16 + (ln & 15);
      int c = hk * 32 + (ln >> 4) * 8 + j;
      Wfrag[idx] = f2bf(weight[(o * Cn + c) * Kn + k]);
    }
    // conv weights: order (k9, half, jt, lane, j); j-rows 27..31 zero
    for (int idx = rb * 256 + t; idx < 18432; idx += 64 * 256) {
      int j    = idx & 7;
      int ln   = (idx >> 3) & 63;
      int jt   = (idx >> 9) & 1;
      int half = (idx >> 10) & 1;
      int k9   = idx >> 11;
      int jo = jt * 16 + (ln & 15);
      int c  = half * 32 + (ln >> 4) * 8 + j;
      float v = (jo < 27) ? w_om[(jo * Cn + c) * Kn + k9] : 0.f;
      WOMfrag[idx] = (_Float16)v;
    }
    if (rb == 0 && t < 256) {
      int b = t >> 6, c = t & 63;
      xT[b * XBSTRIDE + ZROW * 64 + c] = 0;
      xeF[b * XBSTRIDE + ZROW * 64 + c] = (_Float16)0.f;
    }
  }
}

// ---------------------------------------------------------------------------
// K2 fused, barrier-free; k-loop pipelined with sched_barrier(0) pinning:
//   load block  : H (half1, k) + N (half0, k+1) + rec(k+2)
//   ---- sched_barrier(0) ----
//   compute block: A-frags(k), interp, 8x MFMA
// Records pipelined 2-deep in registers so ds_read latency never blocks the
// load block. Every vmcnt wait covers loads issued >=1 compute block earlier.
// ---------------------------------------------------------------------------
__global__ __launch_bounds__(256, 4) void k_fused(
    const unsigned short* __restrict__ xT,
    const _Float16* __restrict__ xeF,
    const unsigned short* __restrict__ Wfrag,
    const _Float16* __restrict__ WOMfrag,
    const float* __restrict__ pre_offset,
    const float* __restrict__ pre_sim,
    const float* __restrict__ b_om,
    const float* __restrict__ bias,
    float* __restrict__ out)
{
  __shared__ float jbuf[4 * 16 * 36];    // per-wave j-values, stride 36
  __shared__ uint4 recbuf[4 * 16 * 9];   // per-wave gather records

  const int t    = threadIdx.x;
  const int lane = t & 63;
  const int wv   = __builtin_amdgcn_readfirstlane(t >> 6);
  const int blk  = blockIdx.x;
  const int b    = blk >> 8;
  const int h    = (blk >> 1) & 127;
  const int wq   = (blk & 1) * 4 + wv;   // 16-pixel group (0..7)
  const int kq   = lane >> 4;            // c-subgroup / j-subgroup
  const int n    = lane & 15;            // pixel within tile
  const int w    = wq * 16 + n;

  // ---- Phase 1: offset conv on MFMA
  unsigned tapoff[9];
  #pragma unroll
  for (int k9 = 0; k9 < 9; ++k9) {
    int r  = h - 1 + k9 / 3;
    int cc = w - 1 + k9 % 3;
    bool v = ((unsigned)r < (unsigned)Hn) & ((unsigned)cc < (unsigned)Wn);
    tapoff[k9] = (v ? (unsigned)(r * Wn + cc) : (unsigned)ZROW) * 64u;
  }

  const _Float16* xe = xeF + b * XBSTRIDE;
  const v8h* Wom = (const v8h*)WOMfrag;
  v4f ca0 = {0,0,0,0}, ca1 = {0,0,0,0};
  for (int k9 = 0; k9 < 9; ++k9) {
    #pragma unroll
    for (int half = 0; half < 2; ++half) {
      int abase = ((k9 * 2 + half) * 2) * 64 + lane;
      v8h A0 = Wom[abase];
      v8h A1 = Wom[abase + 64];
      v8h Bt = *(const v8h*)(xe + tapoff[k9] + half * 32 + kq * 8);
      ca0 = __builtin_amdgcn_mfma_f32_16x16x32_f16(A0, Bt, ca0, 0, 0, 0);
      ca1 = __builtin_amdgcn_mfma_f32_16x16x32_f16(A1, Bt, ca1, 0, 0, 0);
    }
  }

  // D: col=lane&15 (pixel), row=kq*4+reg (j). Stride-36 rows: 2-way = free.
  float* jb = jbuf + wv * (16 * 36);
  *(v4f*)(jb + n * 36 + kq * 4)      = ca0;   // j 0..15
  *(v4f*)(jb + n * 36 + 16 + kq * 4) = ca1;   // j 16..31

  // ---- Phase 2: records (same wave reads its own LDS; lgkmcnt ordering only)
  uint4* rb = recbuf + wv * (16 * 9);
  if (kq < 3) {
    #pragma unroll
    for (int kk = 0; kk < 3; ++kk) {
      int k = kq * 3 + kk;
      float sy = jb[n * 36 + 2 * k]     + b_om[2 * k];
      float sx = jb[n * 36 + 2 * k + 1] + b_om[2 * k + 1];
      float sm = jb[n * 36 + 18 + k]    + b_om[18 + k];
      int pbase = ((b * Kn + k) * Hn + h) * Wn + w;
      float2 po = *(const float2*)(pre_offset + pbase * 2);
      float py = 10.f * tanhf(sy) + po.y + (float)(h - 1 + k / 3);
      float px = 10.f * tanhf(sx) + po.x + (float)(w - 1 + k % 3);
      float m  = 1.f / (1.f + expf(-sm * pre_sim[pbase]));
      float fy = floorf(py), fx = floorf(px);
      float dy = py - fy, dx = px - fx;
      int y0 = (int)fy, x0 = (int)fx;
      int y1 = y0 + 1, x1 = x0 + 1;
      bool vy0 = (y0 >= 0) & (y0 < Hn), vy1 = (y1 >= 0) & (y1 < Hn);
      bool vx0 = (x0 >= 0) & (x0 < Wn), vx1 = (x1 >= 0) & (x1 < Wn);
      unsigned r00 = (vy0 & vx0) ? (unsigned)(y0 * Wn + x0) : ZROW;
      unsigned r01 = (vy0 & vx1) ? (unsigned)(y0 * Wn + x1) : ZROW;
      unsigned r10 = (vy1 & vx0) ? (unsigned)(y1 * Wn + x0) : ZROW;
      unsigned r11 = (vy1 & vx1) ? (unsigned)(y1 * Wn + x1) : ZROW;
      float wy0 = 1.f - dy, wx0 = 1.f - dx;
      uint4 rec;
      rec.x = r00 | (r01 << 16);
      rec.y = r10 | (r11 << 16);
      rec.z = (unsigned)f2h(wy0 * wx0 * m) | ((unsigned)f2h(wy0 * dx * m) << 16);
      rec.w = (unsigned)f2h(dy * wx0 * m) | ((unsigned)f2h(dy * dx * m) << 16);
      rb[n * 9 + k] = rec;
    }
  }

  // ---- Phase 3: main GEMM, sched_barrier-pinned pipeline
  v4f acc0 = {0,0,0,0}, acc1 = {0,0,0,0}, acc2 = {0,0,0,0}, acc3 = {0,0,0,0};
  const unsigned short* xb = xT + b * XBSTRIDE;
  const v8s* Wf = (const v8s*)Wfrag;

  // prologue: rec k0 + k1, k0 weights/offsets, k0 half0 corners
  uint4 rec0   = rb[n * 9 + 0];
  uint4 rec_nx = rb[n * 9 + 1];
  float w00 = h2f(rec0.z), w01 = h2f(rec0.z >> 16);
  float w10 = h2f(rec0.w), w11 = h2f(rec0.w >> 16);
  unsigned o00 = (rec0.x & 0xffff) * 64 + kq * 8;
  unsigned o01 = (rec0.x >> 16)    * 64 + kq * 8;
  unsigned o10 = (rec0.y & 0xffff) * 64 + kq * 8;
  unsigned o11 = (rec0.y >> 16)    * 64 + kq * 8;
  v8s C0 = *(const v8s*)(xb + o00);
  v8s C1 = *(const v8s*)(xb + o01);
  v8s C2 = *(const v8s*)(xb + o10);
  v8s C3 = *(const v8s*)(xb + o11);

  #pragma unroll
  for (int k = 0; k < 9; ++k) {
    // ------- load block -------
    // half1 of k (same 128B lines as half0 -> warm)
    v8s H0 = *(const v8s*)(xb + o00 + 32);
    v8s H1 = *(const v8s*)(xb + o01 + 32);
    v8s H2 = *(const v8s*)(xb + o10 + 32);
    v8s H3 = *(const v8s*)(xb + o11 + 32);

    // half0 of k+1 (addresses from rec_nx, read one iter ago)
    v8s N0, N1, N2, N3;
    float nw00 = 0.f, nw01 = 0.f, nw10 = 0.f, nw11 = 0.f;
    unsigned p00 = 0, p01 = 0, p10 = 0, p11 = 0;
    if (k < 8) {
      nw00 = h2f(rec_nx.z); nw01 = h2f(rec_nx.z >> 16);
      nw10 = h2f(rec_nx.w); nw11 = h2f(rec_nx.w >> 16);
      p00 = (rec_nx.x & 0xffff) * 64 + kq * 8;
      p01 = (rec_nx.x >> 16)    * 64 + kq * 8;
      p10 = (rec_nx.y & 0xffff) * 64 + kq * 8;
      p11 = (rec_nx.y >> 16)    * 64 + kq * 8;
      N0 = *(const v8s*)(xb + p00);
      N1 = *(const v8s*)(xb + p01);
      N2 = *(const v8s*)(xb + p10);
      N3 = *(const v8s*)(xb + p11);
    }
    // rec for k+2 (consumed next iter -> ds latency fully hidden)
    uint4 rec_nx2 = rec_nx;
    if (k < 7) rec_nx2 = rb[n * 9 + k + 2];

    // ------- pin: loads above, compute below -------
    __builtin_amdgcn_sched_barrier(0);

    // A-fragments for k (L1/L2-hot)
    const v8s* wk = Wf + (k * 8) * 64 + lane;
    v8s A0 = wk[0 * 64], A1 = wk[1 * 64], A2 = wk[2 * 64], A3 = wk[3 * 64];
    v8s A4 = wk[4 * 64], A5 = wk[5 * 64], A6 = wk[6 * 64], A7 = wk[7 * 64];

    v8s Bf0, Bf1;
    #pragma unroll
    for (int j = 0; j < 8; ++j) {
      float s = fmaf(bf2f((unsigned short)C0[j]), w00,
                fmaf(bf2f((unsigned short)C1[j]), w01,
                fmaf(bf2f((unsigned short)C2[j]), w10,
                     bf2f((unsigned short)C3[j]) * w11)));
      Bf0[j] = (short)f2bf(s);
    }
    #pragma unroll
    for (int j = 0; j < 8; ++j) {
      float s = fmaf(bf2f((unsigned short)H0[j]), w00,
                fmaf(bf2f((unsigned short)H1[j]), w01,
                fmaf(bf2f((unsigned short)H2[j]), w10,
                     bf2f((unsigned short)H3[j]) * w11)));
      Bf1[j] = (short)f2bf(s);
    }

    acc0 = __builtin_amdgcn_mfma_f32_16x16x32_bf16(A0, Bf0, acc0, 0, 0, 0);
    acc1 = __builtin_amdgcn_mfma_f32_16x16x32_bf16(A2, Bf0, acc1, 0, 0, 0);
    acc2 = __builtin_amdgcn_mfma_f32_16x16x32_bf16(A4, Bf0, acc2, 0, 0, 0);
    acc3 = __builtin_amdgcn_mfma_f32_16x16x32_bf16(A6, Bf0, acc3, 0, 0, 0);
    acc0 = __builtin_amdgcn_mfma_f32_16x16x32_bf16(A1, Bf1, acc0, 0, 0, 0);
    acc1 = __builtin_amdgcn_mfma_f32_16x16x32_bf16(A3, Bf1, acc1, 0, 0, 0);
    acc2 = __builtin_amdgcn_mfma_f32_16x16x32_bf16(A5, Bf1, acc2, 0, 0, 0);
    acc3 = __builtin_amdgcn_mfma_f32_16x16x32_bf16(A7, Bf1, acc3, 0, 0, 0);

    // rotate pipeline state
    if (k < 8) {
      C0 = N0; C1 = N1; C2 = N2; C3 = N3;
      w00 = nw00; w01 = nw01; w10 = nw10; w11 = nw11;
      o00 = p00; o01 = p01; o10 = p10; o11 = p11;
      rec_nx = rec_nx2;
    }
  }

  // epilogue: D col=lane&15 (pix), row=kq*4+reg (o within 16-o tile)
  const float4* b4 = (const float4*)bias;
  float4 vb0 = b4[0 * 4 + kq], vb1 = b4[1 * 4 + kq];
  float4 vb2 = b4[2 * 4 + kq], vb3 = b4[3 * 4 + kq];
  float* ob = out + (b * On) * HWn + h * Wn + wq * 16 + n;
  #pragma unroll
  for (int reg = 0; reg < 4; ++reg) {
    ob[(0 * 16 + kq * 4 + reg) * HWn] = acc0[reg] + ((const float*)&vb0)[reg];
    ob[(1 * 16 + kq * 4 + reg) * HWn] = acc1[reg] + ((const float*)&vb1)[reg];
    ob[(2 * 16 + kq * 4 + reg) * HWn] = acc2[reg] + ((const float*)&vb2)[reg];
    ob[(3 * 16 + kq * 4 + reg) * HWn] = acc3[reg] + ((const float*)&vb3)[reg];
  }
}

extern "C" void kernel_launch(void* const* d_in, const int* in_sizes, int n_in,
                              void* d_out, int out_size, void* d_ws, size_t ws_size,
                              hipStream_t stream) {
  const float* x_main     = (const float*)d_in[0];
  const float* x_extra    = (const float*)d_in[1];
  const float* pre_offset = (const float*)d_in[2];
  const float* pre_sim    = (const float*)d_in[3];
  const float* weight     = (const float*)d_in[4];
  const float* bias       = (const float*)d_in[5];
  const float* w_om       = (const float*)d_in[6];
  const float* b_om       = (const float*)d_in[7];
  float* out = (float*)d_out;

  char* ws = (char*)d_ws;
  unsigned short* xT      = (unsigned short*)(ws);              //  8,389,120 B
  _Float16*       xeF     = (_Float16*)(ws + 8389120);          //  8,389,120 B
  unsigned short* Wfrag   = (unsigned short*)(ws + 16778240);   //     73,728 B
  _Float16*       WOMfrag = (_Float16*)(ws + 16851968);         //     36,864 B

  k_prep<<<2112, 256, 0, stream>>>(x_main, x_extra, weight, w_om,
                                   xT, xeF, Wfrag, WOMfrag);
  k_fused<<<1024, 256, 0, stream>>>(xT, xeF, Wfrag, WOMfrag,
                                    pre_offset, pre_sim, b_om, bias, out);
}